// Round 3
// 456.459 us; speedup vs baseline: 1.0144x; 1.0144x over previous
//
#include <hip/hip_runtime.h>

// LocalExpansion: out[b,h,(y,x),c,d] = in[b,h,(y+i-3,x+j-3),d], c = i*7+j,
// zero-filled outside the image. Memory-movement kernel: 462 MB write,
// 9.4 MB input logically read 49x (should be cache-resident).
//
// v10 = v9 with the nontemporal-store type fixed: __builtin_nontemporal_store
// rejects HIP_vector_type<float,4>; use a clang native ext_vector_type(4)
// alias instead (same global_store_dwordx4 ... nt codegen).
// (Round-2 resubmit: previous attempt hit an MI355X container outage;
// source unchanged.)
//
// Theory (round 0): v8's kernel-side time (~160 us inferred: bench dur 463 us
// minus the ~300 us harness poison fill visible in rocprof) sat 2.2x above
// the 73 us write floor. The 462 MB write stream thrashes the 4 MiB per-XCD
// L2s, evicting the 9.4 MB input between its 49 logical re-reads, so reads
// fall to LLC/HBM and contend with write drain. Output has zero reuse ->
// non-temporal stores keep L2 for the input. Harness fills prove nt-style
// streaming stores hit 6.2 TB/s on this chip.
//
// Structure unchanged from v8: 4-deep ILP per wave, block-contiguous unroll —
// thread t of block b handles idx4 = b*1024 + u*256 + t, u=0..3. All 4
// branchless loads (clamped addr + select) issue before the first store;
// every store instruction is 256-lane contiguous; each block writes one
// 16 KB contiguous span.

#define KH 7
#define KW 7
#define HEIGHT 48
#define WIDTH 48
#define DDIM 64
#define NPIX (HEIGHT * WIDTH)   // 2304
#define KK (KH * KW)            // 49
#define UNROLL 4

typedef __attribute__((ext_vector_type(4))) float nt_float4;

__global__ __launch_bounds__(256) void local_expansion_kernel(
    const float* __restrict__ in, float* __restrict__ out) {
    int base4 = blockIdx.x * (256 * UNROLL) + threadIdx.x;

    nt_float4 v[UNROLL];

#pragma unroll
    for (int u = 0; u < UNROLL; ++u) {
        int idx4 = base4 + u * 256;

        // idx4 = ((bh*NPIX + n)*KK + c)*16 + d4
        int d4   = idx4 & 15;
        int rem  = idx4 >> 4;
        int c    = rem % KK;
        int rem2 = rem / KK;
        int n    = rem2 % NPIX;
        int bh   = rem2 / NPIX;

        int y = n / WIDTH;
        int x = n - y * WIDTH;
        int i = c / KW;
        int j = c - i * KW;

        int sy = y + i - (KH - 1) / 2;
        int sx = x + j - (KW - 1) / 2;

        bool inb = ((unsigned)sy < (unsigned)HEIGHT) & ((unsigned)sx < (unsigned)WIDTH);

        // Branchless: clamp to a valid address, load unconditionally, select.
        int syc = min(max(sy, 0), HEIGHT - 1);
        int sxc = min(max(sx, 0), WIDTH - 1);
        int in4 = (bh * NPIX + syc * WIDTH + sxc) * (DDIM / 4) + d4;

        nt_float4 t = ((const nt_float4*)in)[in4];
        nt_float4 z = (nt_float4)(0.f);
        v[u] = inb ? t : z;
    }

#pragma unroll
    for (int u = 0; u < UNROLL; ++u) {
        // Output is write-once, never re-read: non-temporal store keeps the
        // 462 MB stream out of L2 so the 9.4 MB input stays cache-resident.
        __builtin_nontemporal_store(v[u], ((nt_float4*)out) + base4 + u * 256);
    }
}

extern "C" void kernel_launch(void* const* d_in, const int* in_sizes, int n_in,
                              void* d_out, int out_size, void* d_ws, size_t ws_size,
                              hipStream_t stream) {
    const float* x = (const float*)d_in[0];
    float* out = (float*)d_out;

    // out_size = 115,605,504 floats -> 28,901,376 float4s; /(256*4) = 28,224 exact
    int total4 = out_size / 4;
    int blocks = total4 / (256 * UNROLL);
    local_expansion_kernel<<<dim3(blocks), 256, 0, stream>>>(x, out);
}